// Round 1
// baseline (113.424 us; speedup 1.0000x reference)
//
#include <hip/hip_runtime.h>
#include <hip/hip_bf16.h>

typedef __attribute__((ext_vector_type(4))) float f32x4;
typedef __attribute__((ext_vector_type(8))) short s16x8;

#define NODES 100000
#define DIN 256
#define DOUT 128

static __device__ inline unsigned short f2bf(float f) {
    __hip_bfloat16 h = __float2bfloat16(f);
    return __builtin_bit_cast(unsigned short, h);
}
static __device__ inline float bf2f(unsigned short u) {
    __hip_bfloat16 h = __builtin_bit_cast(__hip_bfloat16, u);
    return __bfloat162float(h);
}

// ---------------- prep: W fp32 -> bf16 ; inv_deg from CSR ptr ----------------
__global__ __launch_bounds__(256) void gcn_prep(const float* __restrict__ W,
                                                const int* __restrict__ ptr,
                                                unsigned short* __restrict__ wsW,
                                                float* __restrict__ inv_deg) {
    int t = blockIdx.x * 256 + threadIdx.x;
    if (t < DOUT * DIN) wsW[t] = f2bf(W[t]);
    if (t < NODES) {
        int d = ptr[t + 1] - ptr[t];
        inv_deg[t] = d > 0 ? 1.0f / (float)d : 0.0f;
    }
}

// ---------------- GEMM: h[N,128] (bf16) = x[N,256] @ W.T --------------------
// One wave per 64x128 output tile. No LDS: A frags loaded directly from global
// x (fp32 -> bf16 in regs), B frags directly from bf16 W (L2-hot, 64 KB).
// MFMA 16x16x32 bf16. A: lane holds row=(l&15), k=(l>>4)*8+j (8 contiguous).
// B: lane holds col=(l&15), same k — W[DOUT][DIN] row-major IS this layout.
// C/D: col=lane&15, row=(lane>>4)*4+reg.
__global__ __launch_bounds__(256) void gcn_gemm(const float* __restrict__ x,
                                                const unsigned short* __restrict__ wsW,
                                                unsigned short* __restrict__ h) {
    const int lane = threadIdx.x & 63;
    const int wid  = threadIdx.x >> 6;
    const int gwid = blockIdx.x * 4 + wid;
    const int row0 = gwid * 64;
    if (row0 >= NODES) return;
    const int lr = lane & 15;
    const int lg = lane >> 4;

    f32x4 acc[4][8];
#pragma unroll
    for (int m = 0; m < 4; ++m)
#pragma unroll
        for (int n = 0; n < 8; ++n) acc[m][n] = (f32x4)(0.0f);

    for (int ks = 0; ks < 8; ++ks) {
        const int k0 = ks * 32 + lg * 8;
        s16x8 bf[8];
#pragma unroll
        for (int n = 0; n < 8; ++n) {
            const int col = n * 16 + lr;
            bf[n] = *reinterpret_cast<const s16x8*>(wsW + col * DIN + k0);
        }
#pragma unroll
        for (int m = 0; m < 4; ++m) {
            int row = row0 + m * 16 + lr;
            row = row < NODES ? row : NODES - 1;   // clamp; garbage rows never stored
            const float* xp = x + (long)row * DIN + k0;
            const f32x4 f0 = *reinterpret_cast<const f32x4*>(xp);
            const f32x4 f1 = *reinterpret_cast<const f32x4*>(xp + 4);
            s16x8 af;
            af[0] = (short)f2bf(f0[0]); af[1] = (short)f2bf(f0[1]);
            af[2] = (short)f2bf(f0[2]); af[3] = (short)f2bf(f0[3]);
            af[4] = (short)f2bf(f1[0]); af[5] = (short)f2bf(f1[1]);
            af[6] = (short)f2bf(f1[2]); af[7] = (short)f2bf(f1[3]);
#pragma unroll
            for (int n = 0; n < 8; ++n)
                acc[m][n] = __builtin_amdgcn_mfma_f32_16x16x32_bf16(af, bf[n], acc[m][n], 0, 0, 0);
        }
    }

#pragma unroll
    for (int m = 0; m < 4; ++m) {
        const int rbase = row0 + m * 16 + lg * 4;
#pragma unroll
        for (int n = 0; n < 8; ++n) {
            const int col = n * 16 + lr;
#pragma unroll
            for (int r = 0; r < 4; ++r) {
                const int row = rbase + r;
                if (row < NODES) h[(long)row * DOUT + col] = f2bf(acc[m][n][r]);
            }
        }
    }
}

// ---------------- Aggregation: out[i] = inv_deg[i] * sum_e h[idx[e]] --------
// One wave per node; lane owns channels {2*lane, 2*lane+1} -> one coalesced
// 4B load (2 bf16) per edge per lane = 256B per row per wave. deg <= 32 by
// construction, so a single lane-preload of idx covers all edges.
__global__ __launch_bounds__(256) void gcn_agg(const int* __restrict__ ptr,
                                               const int* __restrict__ idx,
                                               const unsigned short* __restrict__ h,
                                               const float* __restrict__ inv_deg,
                                               float* __restrict__ out) {
    const int lane = threadIdx.x & 63;
    const int wid  = threadIdx.x >> 6;
    const int node = blockIdx.x * 4 + wid;
    if (node >= NODES) return;
    const int p0  = ptr[node];
    const int deg = ptr[node + 1] - p0;

    int src = 0;
    if (lane < deg) src = idx[p0 + lane];

    float a0 = 0.f, a1 = 0.f, b0 = 0.f, b1 = 0.f;
    float c0 = 0.f, c1 = 0.f, d0 = 0.f, d1 = 0.f;
    int e = 0;
    for (; e + 4 <= deg; e += 4) {
        const int s0 = __shfl(src, e);
        const int s1 = __shfl(src, e + 1);
        const int s2 = __shfl(src, e + 2);
        const int s3 = __shfl(src, e + 3);
        const unsigned int v0 = *reinterpret_cast<const unsigned int*>(h + (long)s0 * DOUT + lane * 2);
        const unsigned int v1 = *reinterpret_cast<const unsigned int*>(h + (long)s1 * DOUT + lane * 2);
        const unsigned int v2 = *reinterpret_cast<const unsigned int*>(h + (long)s2 * DOUT + lane * 2);
        const unsigned int v3 = *reinterpret_cast<const unsigned int*>(h + (long)s3 * DOUT + lane * 2);
        a0 += bf2f((unsigned short)(v0 & 0xffffu)); a1 += bf2f((unsigned short)(v0 >> 16));
        b0 += bf2f((unsigned short)(v1 & 0xffffu)); b1 += bf2f((unsigned short)(v1 >> 16));
        c0 += bf2f((unsigned short)(v2 & 0xffffu)); c1 += bf2f((unsigned short)(v2 >> 16));
        d0 += bf2f((unsigned short)(v3 & 0xffffu)); d1 += bf2f((unsigned short)(v3 >> 16));
    }
    for (; e < deg; ++e) {
        const int s0 = __shfl(src, e);
        const unsigned int v0 = *reinterpret_cast<const unsigned int*>(h + (long)s0 * DOUT + lane * 2);
        a0 += bf2f((unsigned short)(v0 & 0xffffu)); a1 += bf2f((unsigned short)(v0 >> 16));
    }
    const float w = inv_deg[node];
    float2 o;
    o.x = (a0 + b0 + c0 + d0) * w;
    o.y = (a1 + b1 + c1 + d1) * w;
    *reinterpret_cast<float2*>(out + (long)node * DOUT + lane * 2) = o;
}

extern "C" void kernel_launch(void* const* d_in, const int* in_sizes, int n_in,
                              void* d_out, int out_size, void* d_ws, size_t ws_size,
                              hipStream_t stream) {
    const float* x   = (const float*)d_in[0];
    const float* W   = (const float*)d_in[1];
    const int*   ptr = (const int*)d_in[2];
    const int*   idx = (const int*)d_in[3];
    // d_in[4] (dst) unused: CSR ptr encodes destinations.
    float* out = (float*)d_out;

    char* ws = (char*)d_ws;
    unsigned short* wsW     = (unsigned short*)ws;               // 64 KB
    float*          inv_deg = (float*)(ws + (64 << 10));         // 400 KB
    unsigned short* h       = (unsigned short*)(ws + (1 << 20)); // 25.6 MB

    gcn_prep<<<391, 256, 0, stream>>>(W, ptr, wsW, inv_deg);
    // ceil(100000/64) = 1563 waves -> 391 blocks x 4 waves
    gcn_gemm<<<391, 256, 0, stream>>>(x, wsW, h);
    // 100000 nodes / 4 waves per block
    gcn_agg<<<25000, 256, 0, stream>>>(ptr, idx, h, inv_deg, out);
}